// Round 7
// baseline (60.812 us; speedup 1.0000x reference)
//
#include <hip/hip_runtime.h>

// B=8, NA=NB=2048, in=256, D=64
typedef short bf16x8 __attribute__((ext_vector_type(8)));
typedef float f32x4 __attribute__((ext_vector_type(4)));
typedef float f32x16 __attribute__((ext_vector_type(16)));

__device__ __forceinline__ unsigned short f2bf(float x) {
  unsigned u = __float_as_uint(x);
  u += 0x7FFFu + ((u >> 16) & 1u);
  return (unsigned short)(u >> 16);
}
__device__ __forceinline__ float bf2f(unsigned short h) {
  return __uint_as_float(((unsigned)h) << 16);
}

// ============ zB: z_B^T (bf16) + sB + per-block max(sB) ============
__global__ __launch_bounds__(256) void zb_kernel(
    const float* __restrict__ hB, const float* __restrict__ WB_w,
    const float* __restrict__ WB_b, const float* __restrict__ aB_w,
    const float* __restrict__ aB_b,
    unsigned short* __restrict__ zBT, float* __restrict__ sB,
    float* __restrict__ msB_blk) {
  __shared__ char wt[32768];   // [64 f][256 k] bf16, 512B rows, XOR swizzle
  __shared__ char hl[16384];   // [32 m][256 k] bf16; reused as zt
  __shared__ float redp[4][16];
  __shared__ float sred[32];

  const int t = threadIdx.x, w = t >> 6, l = t & 63;
  const int q = l >> 4, ln = l & 15;
  const int m0g = blockIdx.x * 32;
  const int b = m0g >> 11, mloc = m0g & 2047;

  {  // stage wt[f][k] = bf16(WB_w[k][f])
    const int f = t >> 2, kseg = t & 3;
    #pragma unroll
    for (int j = 0; j < 8; ++j) {
      const int k0 = kseg * 64 + j * 8;
      bf16x8 v;
      #pragma unroll
      for (int jj = 0; jj < 8; ++jj)
        v[jj] = (short)f2bf(WB_w[(k0 + jj) * 64 + f]);
      *(bf16x8*)(wt + ((f * 512 + k0 * 2) ^ ((f & 7) << 4))) = v;
    }
  }
  {  // stage hl[row][k] = bf16(hB[m0g+row][k])
    #pragma unroll
    for (int i = 0; i < 8; ++i) {
      const int idx = i * 1024 + t * 4;
      const int row = idx >> 8, k = idx & 255;
      const float4 x = *(const float4*)(hB + (size_t)m0g * 256 + idx);
      uint2 pk;
      pk.x = (unsigned)f2bf(x.x) | ((unsigned)f2bf(x.y) << 16);
      pk.y = (unsigned)f2bf(x.z) | ((unsigned)f2bf(x.w) << 16);
      *(uint2*)(hl + ((row * 512 + k * 2) ^ ((row & 7) << 4))) = pk;
    }
  }
  __syncthreads();
  const int rt = w & 1, fpair = w >> 1;
  f32x4 acc[2];
  acc[0] = (f32x4){0.f, 0.f, 0.f, 0.f};
  acc[1] = acc[0];
  const int rowA = rt * 16 + ln;
  #pragma unroll
  for (int kk = 0; kk < 8; ++kk) {
    const int ko = kk * 64 + q * 16;
    const bf16x8 a = *(const bf16x8*)(hl + ((rowA * 512 + ko) ^ ((rowA & 7) << 4)));
    #pragma unroll
    for (int j = 0; j < 2; ++j) {
      const int f = fpair * 32 + j * 16 + ln;
      const bf16x8 bb = *(const bf16x8*)(wt + ((f * 512 + ko) ^ ((f & 7) << 4)));
      acc[j] = __builtin_amdgcn_mfma_f32_16x16x32_bf16(a, bb, acc[j], 0, 0, 0);
    }
  }
  float z[2][4];
  float p[4] = {0.f, 0.f, 0.f, 0.f};
  #pragma unroll
  for (int j = 0; j < 2; ++j) {
    const int f = fpair * 32 + j * 16 + ln;
    const float bias = WB_b[f], aw = aB_w[f];
    #pragma unroll
    for (int r = 0; r < 4; ++r) {
      const float zz = acc[j][r] + bias;
      z[j][r] = zz;
      p[r] += zz * aw;
    }
  }
  #pragma unroll
  for (int r = 0; r < 4; ++r) {
    #pragma unroll
    for (int off = 1; off < 16; off <<= 1) p[r] += __shfl_xor(p[r], off, 16);
  }
  if (ln == 0) {
    #pragma unroll
    for (int r = 0; r < 4; ++r) redp[w][q * 4 + r] = p[r];
  }
  __syncthreads();
  char* zt = hl;
  #pragma unroll
  for (int j = 0; j < 2; ++j) {
    const int f = fpair * 32 + j * 16 + ln;
    uint2 pk;
    pk.x = (unsigned)f2bf(z[j][0]) | ((unsigned)f2bf(z[j][1]) << 16);
    pk.y = (unsigned)f2bf(z[j][2]) | ((unsigned)f2bf(z[j][3]) << 16);
    *(uint2*)(zt + f * 80 + (rt * 16 + q * 4) * 2) = pk;
  }
  if (t < 32) {
    const int rtm = t >> 4, mi = t & 15;
    const float s = redp[rtm][mi] + redp[rtm + 2][mi] + aB_b[0];
    sB[m0g + t] = s;
    sred[t] = s;
  }
  __syncthreads();
  if (t == 0) {
    float bm = sred[0];
    #pragma unroll
    for (int i = 1; i < 32; ++i) bm = fmaxf(bm, sred[i]);
    msB_blk[blockIdx.x] = bm;
  }
  {
    const int f = t >> 2, mseg = t & 3;
    const bf16x8 v = *(const bf16x8*)(zt + f * 80 + mseg * 16);
    *(bf16x8*)(zBT + (size_t)b * 131072 + f * 2048 + mloc + mseg * 8) = v;
  }
}

// ============ gat: fused scores+softmax+PV (64 rows/block, 32x32x16 PV) ======
struct Pref {
  bf16x8 za, zb2;
  uint2 mk0, mk1;
};

__device__ __forceinline__ uint2 pack_mask32(const int* p) {
  const int4 a = *(const int4*)p;
  const int4 c = *(const int4*)(p + 4);
  uint2 r;
  r.x = (a.x ? 1u : 0u) | (a.y ? 0x100u : 0u) | (a.z ? 0x10000u : 0u) | (a.w ? 0x1000000u : 0u);
  r.y = (c.x ? 1u : 0u) | (c.y ? 0x100u : 0u) | (c.z ? 0x10000u : 0u) | (c.w ? 0x1000000u : 0u);
  return r;
}

__device__ __forceinline__ void gat_load(Pref& p, const unsigned short* zrow,
    const unsigned char* mk8a, const unsigned char* mk8b,
    const int* mk32a, const int* mk32b, const bool use8, const int m0) {
  p.za = *(const bf16x8*)(zrow + m0);
  p.zb2 = *(const bf16x8*)(zrow + m0 + 8);
  if (use8) {
    p.mk0 = *(const uint2*)(mk8a + m0);
    p.mk1 = *(const uint2*)(mk8b + m0);
  } else {
    p.mk0 = pack_mask32(mk32a + m0);
    p.mk1 = pack_mask32(mk32b + m0);
  }
}

__device__ __forceinline__ void gat_body(const Pref& p, char* zc, char* wc,
    const float* sBl, const int m0, const int m8,
    const float sA0, const float sA1, const float M0, const float M1,
    const int zw0, const int zw1, const int wbyte0, float& ds0, float& ds1) {
  *(bf16x8*)(zc + zw0) = p.za;
  *(bf16x8*)(zc + zw1) = p.zb2;
  const int sbase = m0 + m8 * 8;
  const float4 s0 = *(const float4*)(sBl + sbase);
  const float4 s1 = *(const float4*)(sBl + sbase + 4);
  const float sbx[8] = {s0.x, s0.y, s0.z, s0.w, s1.x, s1.y, s1.z, s1.w};
  unsigned km0[8], km1[8];
  #pragma unroll
  for (int j = 0; j < 4; ++j) {
    km0[j] = (p.mk0.x >> (8 * j)) & 0xFFu; km0[j + 4] = (p.mk0.y >> (8 * j)) & 0xFFu;
    km1[j] = (p.mk1.x >> (8 * j)) & 0xFFu; km1[j + 4] = (p.mk1.y >> (8 * j)) & 0xFFu;
  }
  unsigned short w0[8], w1[8];
  #pragma unroll
  for (int j = 0; j < 8; ++j) {
    const float x0 = sA0 + sbx[j];
    const float e0 = x0 >= 0.f ? x0 : 0.01f * x0;
    const float v0 = km0[j] ? __expf(e0 - M0) : 0.f;
    w0[j] = f2bf(v0); ds0 += bf2f(w0[j]);
    const float x1 = sA1 + sbx[j];
    const float e1 = x1 >= 0.f ? x1 : 0.01f * x1;
    const float v1 = km1[j] ? __expf(e1 - M1) : 0.f;
    w1[j] = f2bf(v1); ds1 += bf2f(w1[j]);
  }
  uint4 pk0, pk1;
  pk0.x = (unsigned)w0[0] | ((unsigned)w0[1] << 16);
  pk0.y = (unsigned)w0[2] | ((unsigned)w0[3] << 16);
  pk0.z = (unsigned)w0[4] | ((unsigned)w0[5] << 16);
  pk0.w = (unsigned)w0[6] | ((unsigned)w0[7] << 16);
  pk1.x = (unsigned)w1[0] | ((unsigned)w1[1] << 16);
  pk1.y = (unsigned)w1[2] | ((unsigned)w1[3] << 16);
  pk1.z = (unsigned)w1[4] | ((unsigned)w1[5] << 16);
  pk1.w = (unsigned)w1[6] | ((unsigned)w1[7] << 16);
  *(uint4*)(wc + wbyte0) = pk0;
  *(uint4*)(wc + wbyte0 + 8192) = pk1;  // row+32: +32*256, same swizzle bits
}

__device__ __forceinline__ void gat_mfma(const char* zc, const char* wc,
    f32x16& acc, const int abase, const int aswz, const int bbase, const int bswz) {
  #pragma unroll
  for (int ks = 0; ks < 4; ++ks) {
    const bf16x8 aa = *(const bf16x8*)(wc + ((abase + ks * 32) ^ aswz));
    const bf16x8 bb = *(const bf16x8*)(zc + ((bbase + ks * 32) ^ bswz));
    acc = __builtin_amdgcn_mfma_f32_32x32x16_bf16(aa, bb, acc, 0, 0, 0);
  }
}

__global__ __launch_bounds__(512, 4) void gat_kernel(
    const unsigned short* __restrict__ zBT, const float* __restrict__ hA,
    const float* __restrict__ WA_w, const float* __restrict__ WA_b,
    const float* __restrict__ aA_w, const float* __restrict__ aA_b,
    const float* __restrict__ sB, const float* __restrict__ msB_blk,
    const unsigned char* __restrict__ mask8, const int* __restrict__ mask32,
    float* __restrict__ out) {
  const int b = blockIdx.y, n0 = blockIdx.x * 64;
  const int t = threadIdx.x, w = t >> 6, l = t & 63;

  __shared__ char zbl0[16384], zbl1[16384];  // [64 f][128 m] bf16, xor16 swizzle
  __shared__ char wl0[16384], wl1[16384];    // [64 n][128 m] bf16, xor16 swizzle
  __shared__ float sBl[2048];
  __shared__ float vAl[256];
  __shared__ float sAl[64];
  __shared__ float dl[64];
  __shared__ float cAl;
  __shared__ unsigned dfl[4];

  // ---- phase 0: detect, vA, cA, sB preload, msB, sA(64 rows) ----
  if (t < 256) {
    const unsigned vdet = mask8[t * 4 + 1];  // 0 for int32/fp32 0/1; random for bool
    const unsigned long long bal = __ballot(vdet != 0);
    if (l == 0) dfl[w] = (bal != 0ull) ? 1u : 0u;
    float s = 0.f;
    const float4* wr = (const float4*)(WA_w + t * 64);
    const float4* a4 = (const float4*)aA_w;
    #pragma unroll
    for (int i = 0; i < 16; ++i) {
      const float4 x = wr[i], y = a4[i];
      s += x.x * y.x + x.y * y.y + x.z * y.z + x.w * y.w;
    }
    vAl[t] = s;
  } else {
    const int u = t - 256;
    ((float4*)sBl)[u * 2] = ((const float4*)(sB + b * 2048))[u * 2];
    ((float4*)sBl)[u * 2 + 1] = ((const float4*)(sB + b * 2048))[u * 2 + 1];
    if (u == 0) {
      float ca = aA_b[0];
      for (int f = 0; f < 64; ++f) ca += WA_b[f] * aA_w[f];
      cAl = ca;
    }
  }
  float mb = msB_blk[b * 64 + l];
  #pragma unroll
  for (int off = 1; off < 64; off <<= 1) mb = fmaxf(mb, __shfl_xor(mb, off, 64));
  __syncthreads();
  const bool use8 = (dfl[0] | dfl[1] | dfl[2] | dfl[3]) != 0;
  {
    const float4 vA4 = ((const float4*)vAl)[l];
    const float cA0 = cAl;
    #pragma unroll
    for (int rr = 0; rr < 8; ++rr) {
      const int row = w * 8 + rr;
      const float4 h4 = *(const float4*)(hA + ((size_t)(b * 2048 + n0 + row)) * 256 + l * 4);
      float s = h4.x * vA4.x + h4.y * vA4.y + h4.z * vA4.z + h4.w * vA4.w;
      #pragma unroll
      for (int off = 1; off < 64; off <<= 1) s += __shfl_xor(s, off, 64);
      if (l == 0) sAl[row] = s + cA0;
    }
  }
  __syncthreads();

  // ---- per-thread setup ----
  const int r0 = t >> 4, m8 = t & 15;        // rows r0, r0+32; 8 m's each
  const float sA0 = sAl[r0], sA1 = sAl[r0 + 32];
  const float M0f = sA0 + mb, M1f = sA1 + mb;
  const float M0 = M0f >= 0.f ? M0f : 0.01f * M0f;
  const float M1 = M1f >= 0.f ? M1f : 0.01f * M1f;
  float ds0 = 0.f, ds1 = 0.f;
  f32x16 acc;
  #pragma unroll
  for (int i = 0; i < 16; ++i) acc[i] = 0.f;

  const int zf = t >> 3, zseg = t & 7;
  const unsigned short* zrow = zBT + (size_t)b * 131072 + zf * 2048 + zseg * 16;
  const int zswz = (zf & 15) << 4;
  const int zw0 = (zf * 256 + zseg * 32) ^ zswz;
  const int zw1 = (zf * 256 + zseg * 32 + 16) ^ zswz;
  const size_t mrow0 = ((size_t)(b * 2048 + n0 + r0)) * 2048 + m8 * 8;
  const size_t mrow1 = mrow0 + (size_t)32 * 2048;
  const unsigned char* mk8a = mask8 + mrow0;
  const unsigned char* mk8b = mask8 + mrow1;
  const int* mk32a = mask32 + mrow0;
  const int* mk32b = mask32 + mrow1;
  const int wbyte0 = (r0 * 256 + m8 * 16) ^ ((r0 & 15) << 4);
  // wave -> (n-half, f-half, m-half)
  const int wn = w & 1, wf = (w >> 1) & 1, wm = w >> 2;
  const int arow = wn * 32 + (l & 31);
  const int brow = wf * 32 + (l & 31);
  const int abase = arow * 256 + wm * 128 + (l >> 5) * 16;
  const int bbase = brow * 256 + wm * 128 + (l >> 5) * 16;
  const int aswz = (arow & 15) << 4;
  const int bswz = (brow & 15) << 4;

  // ---- main loop: 16 m-tiles of 128, double-buffered, 1 barrier/tile ----
  Pref pA, pB;
  gat_load(pA, zrow, mk8a, mk8b, mk32a, mk32b, use8, 0);
  for (int mt = 0; mt < 16; mt += 2) {
    gat_load(pB, zrow, mk8a, mk8b, mk32a, mk32b, use8, (mt + 1) * 128);
    gat_body(pA, zbl0, wl0, sBl, mt * 128, m8, sA0, sA1, M0, M1, zw0, zw1, wbyte0, ds0, ds1);
    __syncthreads();
    gat_mfma(zbl0, wl0, acc, abase, aswz, bbase, bswz);
    gat_load(pA, zrow, mk8a, mk8b, mk32a, mk32b, use8, ((mt + 2) & 15) * 128);
    gat_body(pB, zbl1, wl1, sBl, (mt + 1) * 128, m8, sA0, sA1, M0, M1, zw0, zw1, wbyte0, ds0, ds1);
    __syncthreads();
    gat_mfma(zbl1, wl1, acc, abase, aswz, bbase, bswz);
  }

  // ---- epilogue: denom, merge m-halves, divide, store ----
  #pragma unroll
  for (int off = 1; off < 16; off <<= 1) {
    ds0 += __shfl_xor(ds0, off, 16);
    ds1 += __shfl_xor(ds1, off, 16);
  }
  if (m8 == 0) { dl[r0] = ds0; dl[r0 + 32] = ds1; }
  __syncthreads();
  float* mrg = (float*)zbl0;  // 16 KB: 4 quadrants x 32x32 f32
  const int quad = (wn * 2 + wf) * 1024;
  if (wm == 1) {
    #pragma unroll
    for (int r = 0; r < 16; ++r) {
      const int row = (r & 3) + 8 * (r >> 2) + 4 * (l >> 5);
      mrg[quad + row * 32 + (l & 31)] = acc[r];
    }
  }
  __syncthreads();
  if (wm == 0) {
    #pragma unroll
    for (int r = 0; r < 16; ++r) {
      const int row = (r & 3) + 8 * (r >> 2) + 4 * (l >> 5);
      const float v = acc[r] + mrg[quad + row * 32 + (l & 31)];
      const int n = wn * 32 + row;
      const float d = dl[n];
      out[((size_t)(b * 2048 + n0 + n)) * 64 + wf * 32 + (l & 31)] = d > 0.f ? v / d : 0.f;
    }
  }
}

extern "C" void kernel_launch(void* const* d_in, const int* in_sizes, int n_in,
                              void* d_out, int out_size, void* d_ws, size_t ws_size,
                              hipStream_t stream) {
  const float* h_A = (const float*)d_in[0];
  const float* h_B = (const float*)d_in[1];
  const unsigned char* mask8 = (const unsigned char*)d_in[2];
  const int* mask32 = (const int*)d_in[2];
  const float* WA_w = (const float*)d_in[3];
  const float* WA_b = (const float*)d_in[4];
  const float* WB_w = (const float*)d_in[5];
  const float* WB_b = (const float*)d_in[6];
  const float* aA_w = (const float*)d_in[7];
  const float* aA_b = (const float*)d_in[8];
  const float* aB_w = (const float*)d_in[9];
  const float* aB_b = (const float*)d_in[10];
  float* out = (float*)d_out;

  char* wsb = (char*)d_ws;
  unsigned short* zBT = (unsigned short*)wsb;        // 2,097,152 B
  float* sB      = (float*)(wsb + 2097152);          // 65,536 B
  float* msB_blk = (float*)(wsb + 2162688);          // 2,048 B

  zb_kernel<<<512, 256, 0, stream>>>(h_B, WB_w, WB_b, aB_w, aB_b, zBT, sB, msB_blk);
  gat_kernel<<<dim3(32, 8), 512, 0, stream>>>(zBT, h_A, WA_w, WA_b, aA_w, aA_b,
                                              sB, msB_blk, mask8, mask32, out);
}